// Round 9
// baseline (477.238 us; speedup 1.0000x reference)
//
#include <hip/hip_runtime.h>
#include <hip/hip_bf16.h>

#define NN 384
#define CZ 128
#define NH 4
#define NROWS (NN*NN)
#define LN_EPS 1e-5f
#define LOG2E 1.4426950408889634f
#define QSCALE_L2 (0.17677669529663687f * 1.4426950408889634f)  // 1/sqrt(32) * log2(e)

typedef unsigned short u16;
typedef unsigned int   u32;
typedef __attribute__((ext_vector_type(8))) __bf16 bf16x8;
typedef __attribute__((ext_vector_type(16))) float f32x16;
typedef __attribute__((ext_vector_type(2))) float f32x2;

__device__ __forceinline__ float bflo(u32 u) { union { u32 i; float f; } a; a.i = u << 16; return a.f; }
__device__ __forceinline__ float bfhi(u32 u) { union { u32 i; float f; } a; a.i = u & 0xffff0000u; return a.f; }
__device__ __forceinline__ u32 cvtpk(float lo, float hi) {
  u32 r; asm("v_cvt_pk_bf16_f32 %0, %1, %2" : "=v"(r) : "v"(lo), "v"(hi)); return r;
}
__device__ __forceinline__ float exp2fast(float x) {
  float r; asm("v_exp_f32 %0, %1" : "=v"(r) : "v"(x)); return r;
}
__device__ __forceinline__ float sigm(float x) {
  return 1.f / (1.f + exp2fast(-x * LOG2E));
}
__device__ __forceinline__ f32x2 pkadd(f32x2 a, f32x2 b) {
  f32x2 d; asm("v_pk_add_f32 %0, %1, %2" : "=v"(d) : "v"(a), "v"(b)); return d;
}

// ---------------- Kernel 1: LayerNorm -> x(bf16), pair_bias (fp32*log2e) ---
__global__ __launch_bounds__(256) void k_ln(const float* __restrict__ act,
    const float* __restrict__ lnw, const float* __restrict__ lnb,
    const float* __restrict__ w2d, u16* __restrict__ xbf, float* __restrict__ pb) {
  int t = threadIdx.x;
  int l32 = t & 31;
  int r = blockIdx.x * 8 + (t >> 5);
  const float4 a = *(const float4*)(act + (size_t)r * CZ + l32 * 4);
  float s = (a.x + a.y) + (a.z + a.w);
  float s2 = (a.x * a.x + a.y * a.y) + (a.z * a.z + a.w * a.w);
  #pragma unroll
  for (int m = 16; m >= 1; m >>= 1) { s += __shfl_xor(s, m, 32); s2 += __shfl_xor(s2, m, 32); }
  float mu = s * (1.0f / CZ);
  float inv = rsqrtf(s2 * (1.0f / CZ) - mu * mu + LN_EPS);
  float4 w = *(const float4*)(lnw + l32 * 4);
  float4 b = *(const float4*)(lnb + l32 * 4);
  float4 xv;
  xv.x = (a.x - mu) * inv * w.x + b.x;
  xv.y = (a.y - mu) * inv * w.y + b.y;
  xv.z = (a.z - mu) * inv * w.z + b.z;
  xv.w = (a.w - mu) * inv * w.w + b.w;
  uint2 st; st.x = cvtpk(xv.x, xv.y); st.y = cvtpk(xv.z, xv.w);
  *(uint2*)(xbf + (size_t)r * CZ + l32 * 4) = st;
  #pragma unroll
  for (int h = 0; h < NH; ++h) {
    float4 wd = *(const float4*)(w2d + h * CZ + l32 * 4);
    float p = (xv.x * wd.x + xv.y * wd.y) + (xv.z * wd.z + xv.w * wd.w);
    #pragma unroll
    for (int m = 16; m >= 1; m >>= 1) p += __shfl_xor(p, m, 32);
    if (l32 == 0) pb[(size_t)h * NROWS + r] = p * LOG2E;
  }
}

// ---------------- Kernel 2: MFMA projections, one mat per block ------------
__global__ __launch_bounds__(256) void k_projf(const u16* __restrict__ x,
    const float* __restrict__ wq, const float* __restrict__ wk,
    const float* __restrict__ wv, const float* __restrict__ wg,
    const float* __restrict__ bg,
    u16* __restrict__ qb, u16* __restrict__ kb,
    u16* __restrict__ vT, u16* __restrict__ gb) {
  __shared__ __align__(16) u16 wl[128][128];  // 32 KB
  __shared__ __align__(16) u16 xl[64][128];   // 16 KB
  int t = threadIdx.x;
  int lane = t & 63, wid = t >> 6;
  int jl = lane & 31, g = lane >> 5;
  int m = blockIdx.y;
  const float* W = (m == 0) ? wq : (m == 1) ? wk : (m == 2) ? wv : wg;
  float sc = (m == 0) ? QSCALE_L2 : 1.f;
  size_t tile0 = (size_t)blockIdx.x * 9;

  uint4 xr[4];
  {
    const uint4* src = (const uint4*)(x + tile0 * 64 * CZ);
    #pragma unroll
    for (int p = 0; p < 4; ++p) xr[p] = src[t + p * 256];
  }
  #pragma unroll
  for (int it = 0; it < 8; ++it) {
    int idx = t + it * 256;
    int e = idx >> 4, s = idx & 15;
    float4 f0 = *(const float4*)&W[e * CZ + s * 8];
    float4 f1 = *(const float4*)&W[e * CZ + s * 8 + 4];
    uint4 st;
    st.x = cvtpk(f0.x * sc, f0.y * sc); st.y = cvtpk(f0.z * sc, f0.w * sc);
    st.z = cvtpk(f1.x * sc, f1.y * sc); st.w = cvtpk(f1.z * sc, f1.w * sc);
    *(uint4*)&wl[e][(s ^ (e & 15)) * 8] = st;
  }

  int rfb = (wid & 1) * 32, efb = (wid >> 1) * 2;
  for (int it = 0; it < 9; ++it) {
    __syncthreads();
    #pragma unroll
    for (int p = 0; p < 4; ++p) {
      int q = t + p * 256; int r = q >> 4, s = q & 15;
      *(uint4*)&xl[r][(s ^ (r & 15)) * 8] = xr[p];
    }
    __syncthreads();
    if (it < 8) {
      const uint4* src = (const uint4*)(x + (tile0 + it + 1) * 64 * CZ);
      #pragma unroll
      for (int p = 0; p < 4; ++p) xr[p] = src[t + p * 256];
    }
    size_t row0 = (tile0 + it) * 64;

    f32x16 acc[2];
    #pragma unroll
    for (int ef = 0; ef < 2; ++ef)
      #pragma unroll
      for (int i = 0; i < 16; ++i) acc[ef][i] = 0.f;

    if (m == 2) {  // v: mfma(x, W^T) -> C lane = e, regs = row
      #pragma unroll
      for (int ks = 0; ks < 8; ++ks) {
        int r = rfb + jl;
        bf16x8 xa = *(const bf16x8*)&xl[r][((2 * ks + g) ^ (r & 15)) * 8];
        #pragma unroll
        for (int ef = 0; ef < 2; ++ef) {
          int e = (efb + ef) * 32 + jl;
          bf16x8 wf = *(const bf16x8*)&wl[e][((2 * ks + g) ^ (e & 15)) * 8];
          acc[ef] = __builtin_amdgcn_mfma_f32_32x32x16_bf16(xa, wf, acc[ef], 0, 0, 0);
        }
      }
      #pragma unroll
      for (int ef = 0; ef < 2; ++ef) {
        int e = (efb + ef) * 32 + jl;
        u16* dst = vT + (size_t)e * NROWS + row0 + rfb + 4 * g;
        #pragma unroll
        for (int rr = 0; rr < 4; ++rr) {
          uint2 st;
          st.x = cvtpk(acc[ef][4 * rr + 0], acc[ef][4 * rr + 1]);
          st.y = cvtpk(acc[ef][4 * rr + 2], acc[ef][4 * rr + 3]);
          *(uint2*)(dst + 8 * rr) = st;
        }
      }
    } else {  // q/k/g: mfma(W, x^T) -> C lane = row, regs = e
      #pragma unroll
      for (int ks = 0; ks < 8; ++ks) {
        int r = rfb + jl;
        bf16x8 xa = *(const bf16x8*)&xl[r][((2 * ks + g) ^ (r & 15)) * 8];
        #pragma unroll
        for (int ef = 0; ef < 2; ++ef) {
          int e = (efb + ef) * 32 + jl;
          bf16x8 wf = *(const bf16x8*)&wl[e][((2 * ks + g) ^ (e & 15)) * 8];
          acc[ef] = __builtin_amdgcn_mfma_f32_32x32x16_bf16(wf, xa, acc[ef], 0, 0, 0);
        }
      }
      u16* ob = (m == 0) ? qb : (m == 1) ? kb : gb;
      size_t row = row0 + rfb + jl;
      #pragma unroll
      for (int ef = 0; ef < 2; ++ef) {
        u16* dst = ob + row * CZ + (efb + ef) * 32 + 4 * g;
        #pragma unroll
        for (int rr = 0; rr < 4; ++rr) {
          float v0 = acc[ef][4 * rr + 0], v1 = acc[ef][4 * rr + 1];
          float v2 = acc[ef][4 * rr + 2], v3 = acc[ef][4 * rr + 3];
          if (m == 3) {
            float4 bv = *(const float4*)&bg[(efb + ef) * 32 + 8 * rr + 4 * g];
            v0 = sigm(v0 + bv.x); v1 = sigm(v1 + bv.y);
            v2 = sigm(v2 + bv.z); v3 = sigm(v3 + bv.w);
          }
          uint2 st; st.x = cvtpk(v0, v1); st.y = cvtpk(v2, v3);
          *(uint2*)(dst + 8 * rr) = st;
        }
      }
    }
  }
}

// ---------------- Kernel 3: MFMA attention, 12 waves x 1 j-frag, ----------
// software-pipelined kt loop: ka(LDS) + pb(global) for kt+1 issued at the
// top of kt's compute (register ping-pong A/B, static names per rule #20).
// va issued before softmax (its latency hides under QK+softmax). Math is
// bit-identical to R7 (same order, same ops).
template<bool MASKED>
__device__ __forceinline__ void attn_core(const u16* ks, const u16* vs,
    const float* pbj, const float* mrow4, int jl, int g,
    bf16x8 qf0, bf16x8 qf1, f32x16& oacc, float& mrun, float& lrun) {
  bf16x8 kaA0, kaA1, kaB0, kaB1;
  float4 pbA[4], pbB[4];
  kaA0 = *(const bf16x8*)&ks[jl * 40 + 8 * g];
  kaA1 = *(const bf16x8*)&ks[jl * 40 + 8 * g + 16];
  #pragma unroll
  for (int m4 = 0; m4 < 4; ++m4) pbA[m4] = *(const float4*)(pbj + 8 * m4);

#define ATTN_STEP(CUR, NXT, KT)                                                \
  {                                                                            \
    const int k0 = (KT) * 32;                                                  \
    bf16x8 va0 = *(const bf16x8*)&vs[jl * 392 + k0 + 8 * g];                   \
    bf16x8 va1 = *(const bf16x8*)&vs[jl * 392 + k0 + 16 + 8 * g];              \
    if ((KT) + 1 < 12) {                                                       \
      const int k1 = ((KT) + 1) * 32;                                          \
      ka##NXT##0 = *(const bf16x8*)&ks[(k1 + jl) * 40 + 8 * g];                \
      ka##NXT##1 = *(const bf16x8*)&ks[(k1 + jl) * 40 + 8 * g + 16];           \
      _Pragma("unroll")                                                        \
      for (int m4 = 0; m4 < 4; ++m4)                                           \
        pb##NXT[m4] = *(const float4*)(pbj + k1 + 8 * m4);                     \
    }                                                                          \
    f32x16 sac;                                                                \
    _Pragma("unroll")                                                          \
    for (int r = 0; r < 16; ++r) sac[r] = 0.f;                                 \
    __builtin_amdgcn_s_setprio(1);                                             \
    sac = __builtin_amdgcn_mfma_f32_32x32x16_bf16(ka##CUR##0, qf0, sac, 0, 0, 0); \
    sac = __builtin_amdgcn_mfma_f32_32x32x16_bf16(ka##CUR##1, qf1, sac, 0, 0, 0); \
    __builtin_amdgcn_s_setprio(0);                                             \
    f32x2 s2[8];                                                               \
    _Pragma("unroll")                                                          \
    for (int rr = 0; rr < 4; ++rr) {                                           \
      float4 pv = pb##CUR[rr];                                                 \
      s2[2 * rr + 0] = pkadd(f32x2{sac[4 * rr + 0], sac[4 * rr + 1]},          \
                             f32x2{pv.x, pv.y});                               \
      s2[2 * rr + 1] = pkadd(f32x2{sac[4 * rr + 2], sac[4 * rr + 3]},          \
                             f32x2{pv.z, pv.w});                               \
    }                                                                          \
    if (MASKED) {                                                              \
      _Pragma("unroll")                                                        \
      for (int m4 = 0; m4 < 4; ++m4) {                                         \
        float4 mm = *(const float4*)(mrow4 + k0 + 8 * m4);                     \
        s2[2 * m4 + 0] = pkadd(s2[2 * m4 + 0],                                 \
            f32x2{(mm.x - 1.f) * (1e9f * LOG2E), (mm.y - 1.f) * (1e9f * LOG2E)}); \
        s2[2 * m4 + 1] = pkadd(s2[2 * m4 + 1],                                 \
            f32x2{(mm.z - 1.f) * (1e9f * LOG2E), (mm.w - 1.f) * (1e9f * LOG2E)}); \
      }                                                                        \
    }                                                                          \
    float t0 = fmaxf(fmaxf(s2[0][0], s2[0][1]), fmaxf(s2[1][0], s2[1][1]));    \
    float t1 = fmaxf(fmaxf(s2[2][0], s2[2][1]), fmaxf(s2[3][0], s2[3][1]));    \
    float t2 = fmaxf(fmaxf(s2[4][0], s2[4][1]), fmaxf(s2[5][0], s2[5][1]));    \
    float t3 = fmaxf(fmaxf(s2[6][0], s2[6][1]), fmaxf(s2[7][0], s2[7][1]));    \
    float tmax = fmaxf(fmaxf(t0, t1), fmaxf(t2, t3));                          \
    tmax = fmaxf(tmax, __shfl_xor(tmax, 32, 64));                              \
    float mold = mrun;                                                         \
    bool defer = __all(tmax <= mold + 8.f);                                    \
    float mnew = defer ? mold : fmaxf(mold, tmax);                             \
    f32x2 nmw = f32x2{-mnew, -mnew};                                           \
    f32x2 p2[8];                                                               \
    _Pragma("unroll")                                                          \
    for (int p8 = 0; p8 < 8; ++p8) {                                           \
      f32x2 d = pkadd(s2[p8], nmw);                                            \
      p2[p8] = f32x2{exp2fast(d[0]), exp2fast(d[1])};                          \
    }                                                                          \
    f32x2 q0 = pkadd(p2[0], p2[1]), q1 = pkadd(p2[2], p2[3]);                  \
    f32x2 q2 = pkadd(p2[4], p2[5]), q3 = pkadd(p2[6], p2[7]);                  \
    q0 = pkadd(q0, q1); q2 = pkadd(q2, q3); q0 = pkadd(q0, q2);                \
    float psum = q0[0] + q0[1];                                                \
    if (!defer) {                                                              \
      float rsc = exp2fast(mold - mnew);                                       \
      mrun = mnew;                                                             \
      lrun = lrun * rsc + psum;                                                \
      _Pragma("unroll")                                                        \
      for (int r = 0; r < 16; ++r) oacc[r] *= rsc;                             \
    } else {                                                                   \
      lrun += psum;                                                            \
    }                                                                          \
    u32 A01 = cvtpk(p2[0][0], p2[0][1]), A23 = cvtpk(p2[1][0], p2[1][1]);      \
    u32 B01 = cvtpk(p2[2][0], p2[2][1]), B23 = cvtpk(p2[3][0], p2[3][1]);      \
    u32 C01 = cvtpk(p2[4][0], p2[4][1]), C23 = cvtpk(p2[5][0], p2[5][1]);      \
    u32 D01 = cvtpk(p2[6][0], p2[6][1]), D23 = cvtpk(p2[7][0], p2[7][1]);      \
    auto r0 = __builtin_amdgcn_permlane32_swap(A01, B01, false, false);        \
    auto r1 = __builtin_amdgcn_permlane32_swap(A23, B23, false, false);        \
    auto r2 = __builtin_amdgcn_permlane32_swap(C01, D01, false, false);        \
    auto r3 = __builtin_amdgcn_permlane32_swap(C23, D23, false, false);        \
    union { u32 w[4]; bf16x8 v; } b0, b1;                                      \
    b0.w[0] = r0[0]; b0.w[1] = r1[0]; b0.w[2] = r0[1]; b0.w[3] = r1[1];        \
    b1.w[0] = r2[0]; b1.w[1] = r3[0]; b1.w[2] = r2[1]; b1.w[3] = r3[1];        \
    __builtin_amdgcn_s_setprio(1);                                             \
    oacc = __builtin_amdgcn_mfma_f32_32x32x16_bf16(va0, b0.v, oacc, 0, 0, 0);  \
    oacc = __builtin_amdgcn_mfma_f32_32x32x16_bf16(va1, b1.v, oacc, 0, 0, 0);  \
    __builtin_amdgcn_s_setprio(0);                                             \
  }

  for (int kt = 0; kt < 12; kt += 2) {
    ATTN_STEP(A, B, kt);
    ATTN_STEP(B, A, kt + 1);
  }
#undef ATTN_STEP
}

__global__ __launch_bounds__(768, 5) void k_attn(const u16* __restrict__ q,
    const u16* __restrict__ kmat, const u16* __restrict__ vT,
    const float* __restrict__ pb, const float* __restrict__ mask,
    u16* __restrict__ o) {
  __shared__ __align__(16) u16 ks[384 * 40];  // K rows padded to 40 bf16
  __shared__ __align__(16) u16 vs[32 * 392];  // V^T rows padded to 392 bf16
  int i = blockIdx.x, h = blockIdx.y;
  int t = threadIdx.x;
  size_t base = ((size_t)i * NN) * CZ + h * 32;
  {
    const u16* src = kmat + base;
    for (int idx = t; idx < 1536; idx += 768) {
      int row = idx >> 2, c = idx & 3;
      *(uint4*)&ks[row * 40 + c * 8] = *(const uint4*)(src + (size_t)row * CZ + c * 8);
    }
    const u16* vsrc = vT + (size_t)(h * 32) * NROWS + (size_t)i * NN;
    for (int idx = t; idx < 1536; idx += 768) {
      int d = idx / 48, c = idx % 48;
      *(uint4*)&vs[d * 392 + c * 8] = *(const uint4*)(vsrc + (size_t)d * NROWS + c * 8);
    }
  }
  int lane = t & 63, wid = t >> 6;  // wid 0..11
  int jl = lane & 31, g = lane >> 5;
  int j = wid * 32 + jl;
  const float* mrow = mask + (size_t)i * NN;
  bool m1 = true;
  #pragma unroll
  for (int c = 0; c < 6; ++c) m1 &= (mrow[lane + 64 * c] == 1.f);
  bool nomask = __all(m1);
  const u16* qp = q + base + (size_t)j * CZ + g * 8;
  bf16x8 qf0 = *(const bf16x8*)qp;
  bf16x8 qf1 = *(const bf16x8*)(qp + 16);
  __syncthreads();

  f32x16 oacc;
  #pragma unroll
  for (int r = 0; r < 16; ++r) oacc[r] = 0.f;
  float mrun = -3e38f, lrun = 0.f;
  const float* pbj = pb + (size_t)h * NROWS + (size_t)j * NN + 4 * g;
  if (nomask) attn_core<false>(ks, vs, pbj, mrow + 4 * g, jl, g, qf0, qf1, oacc, mrun, lrun);
  else        attn_core<true >(ks, vs, pbj, mrow + 4 * g, jl, g, qf0, qf1, oacc, mrun, lrun);

  float lt = lrun + __shfl_xor(lrun, 32, 64);
  float inv = 1.f / lt;
  u16* dst = o + (size_t)(i * NN + j) * CZ + h * 32 + 4 * g;
  #pragma unroll
  for (int q4 = 0; q4 < 4; ++q4) {
    uint2 st;
    st.x = cvtpk(oacc[4 * q4 + 0] * inv, oacc[4 * q4 + 1] * inv);
    st.y = cvtpk(oacc[4 * q4 + 2] * inv, oacc[4 * q4 + 3] * inv);
    *(uint2*)(dst + 8 * q4) = st;
  }
}

// ---------------- Kernel 4: MFMA out = (o*g) @ wo^T + bo  (fp32 out) -------
__global__ __launch_bounds__(256) void k_out(const u16* __restrict__ o,
    const u16* __restrict__ g, const float* __restrict__ wo,
    const float* __restrict__ bo, float* __restrict__ out) {
  __shared__ __align__(16) u16 wols[128][128];  // 32 KB
  __shared__ __align__(16) u16 tls[128][128];   // 32 KB
  int t = threadIdx.x;
  int lane = t & 63, wid = t >> 6, jl = lane & 31, gg = lane >> 5;
  size_t row0 = (size_t)blockIdx.x * 128;
  #pragma unroll
  for (int it = 0; it < 8; ++it) {
    int idx = t + it * 256; int c = idx >> 4, s = idx & 15;
    float4 f0 = *(const float4*)&wo[c * CZ + s * 8];
    float4 f1 = *(const float4*)&wo[c * CZ + s * 8 + 4];
    uint4 st; st.x = cvtpk(f0.x, f0.y); st.y = cvtpk(f0.z, f0.w);
    st.z = cvtpk(f1.x, f1.y); st.w = cvtpk(f1.z, f1.w);
    *(uint4*)&wols[c][(s ^ (c & 15)) * 8] = st;
  }
  #pragma unroll
  for (int it = 0; it < 8; ++it) {
    int idx = t + it * 256; int r = idx >> 4, s = idx & 15;
    uint4 uo = *(const uint4*)(o + (row0 + r) * CZ + s * 8);
    uint4 ug = *(const uint4*)(g + (row0 + r) * CZ + s * 8);
    uint4 st;
    st.x = cvtpk(bflo(uo.x) * bflo(ug.x), bfhi(uo.x) * bfhi(ug.x));
    st.y = cvtpk(bflo(uo.y) * bflo(ug.y), bfhi(uo.y) * bfhi(ug.y));
    st.z = cvtpk(bflo(uo.z) * bflo(ug.z), bfhi(uo.z) * bfhi(ug.z));
    st.w = cvtpk(bflo(uo.w) * bflo(ug.w), bfhi(uo.w) * bfhi(ug.w));
    *(uint4*)&tls[r][(s ^ (r & 15)) * 8] = st;
  }
  __syncthreads();
  f32x16 acc[4];
  #pragma unroll
  for (int cf = 0; cf < 4; ++cf)
    #pragma unroll
    for (int i = 0; i < 16; ++i) acc[cf][i] = 0.f;
  #pragma unroll
  for (int ks = 0; ks < 8; ++ks) {
    int r = wid * 32 + jl;
    bf16x8 tf = *(const bf16x8*)&tls[r][((2 * ks + gg) ^ (r & 15)) * 8];
    #pragma unroll
    for (int cf = 0; cf < 4; ++cf) {
      int c = cf * 32 + jl;
      bf16x8 wf = *(const bf16x8*)&wols[c][((2 * ks + gg) ^ (c & 15)) * 8];
      acc[cf] = __builtin_amdgcn_mfma_f32_32x32x16_bf16(wf, tf, acc[cf], 0, 0, 0);
    }
  }
  size_t row = row0 + wid * 32 + jl;
  #pragma unroll
  for (int cf = 0; cf < 4; ++cf)
    #pragma unroll
    for (int rr = 0; rr < 4; ++rr) {
      int c = cf * 32 + 8 * rr + 4 * gg;
      float4 bv = *(const float4*)&bo[c];
      float4 v;
      v.x = acc[cf][4 * rr + 0] + bv.x; v.y = acc[cf][4 * rr + 1] + bv.y;
      v.z = acc[cf][4 * rr + 2] + bv.z; v.w = acc[cf][4 * rr + 3] + bv.w;
      *(float4*)&out[row * CZ + c] = v;
    }
}

extern "C" void kernel_launch(void* const* d_in, const int* in_sizes, int n_in,
                              void* d_out, int out_size, void* d_ws, size_t ws_size,
                              hipStream_t stream) {
  const float* act  = (const float*)d_in[0];
  const float* mask = (const float*)d_in[1];
  const float* ln_w = (const float*)d_in[2];
  const float* ln_b = (const float*)d_in[3];
  const float* w2d  = (const float*)d_in[4];
  const float* wq   = (const float*)d_in[5];
  const float* wk   = (const float*)d_in[6];
  const float* wv   = (const float*)d_in[7];
  const float* wg   = (const float*)d_in[8];
  const float* bg   = (const float*)d_in[9];
  const float* wo   = (const float*)d_in[10];
  const float* bo   = (const float*)d_in[11];
  float* out = (float*)d_out;

  char* ws = (char*)d_ws;
  const size_t sz = (size_t)NROWS * CZ * 2;
  u16* xbf = (u16*)ws;
  u16* qb  = (u16*)(ws + 1 * sz);
  u16* kb  = (u16*)(ws + 2 * sz);
  u16* vTb = (u16*)(ws + 3 * sz);
  u16* gb  = (u16*)(ws + 4 * sz);
  u16* ob  = (u16*)(ws + 5 * sz);
  float* pbf = (float*)(ws + 6 * sz);

  k_ln<<<NROWS / 8, 256, 0, stream>>>(act, ln_w, ln_b, w2d, xbf, pbf);
  dim3 gp(256, 4);
  k_projf<<<gp, 256, 0, stream>>>(xbf, wq, wk, wv, wg, bg, qb, kb, vTb, gb);
  dim3 ga(NN, NH);
  k_attn<<<ga, 768, 0, stream>>>(qb, kb, vTb, pbf, mask, ob);
  k_out<<<NROWS / 128, 256, 0, stream>>>(ob, gb, wo, bo, out);
}

// Round 10
// 289.633 us; speedup vs baseline: 1.6477x; 1.6477x over previous
//
#include <hip/hip_runtime.h>
#include <hip/hip_bf16.h>

#define NN 384
#define CZ 128
#define NH 4
#define NROWS (NN*NN)
#define LN_EPS 1e-5f
#define LOG2E 1.4426950408889634f
#define QSCALE_L2 (0.17677669529663687f * 1.4426950408889634f)  // 1/sqrt(32) * log2(e)

typedef unsigned short u16;
typedef unsigned int   u32;
typedef __attribute__((ext_vector_type(8))) __bf16 bf16x8;
typedef __attribute__((ext_vector_type(16))) float f32x16;
typedef __attribute__((ext_vector_type(2))) float f32x2;

__device__ __forceinline__ float bflo(u32 u) { union { u32 i; float f; } a; a.i = u << 16; return a.f; }
__device__ __forceinline__ float bfhi(u32 u) { union { u32 i; float f; } a; a.i = u & 0xffff0000u; return a.f; }
__device__ __forceinline__ u16 f2bf(float f) {
  union { float f; u32 i; } a; a.f = f;
  u32 r = a.i + 0x7fffu + ((a.i >> 16) & 1u);
  return (u16)(r >> 16);
}
__device__ __forceinline__ u32 cvtpk(float lo, float hi) {
  u32 r; asm("v_cvt_pk_bf16_f32 %0, %1, %2" : "=v"(r) : "v"(lo), "v"(hi)); return r;
}
__device__ __forceinline__ float exp2fast(float x) {
  float r; asm("v_exp_f32 %0, %1" : "=v"(r) : "v"(x)); return r;
}
__device__ __forceinline__ float sigm(float x) {
  return 1.f / (1.f + exp2fast(-x * LOG2E));
}
__device__ __forceinline__ f32x2 pkadd(f32x2 a, f32x2 b) {
  f32x2 d; asm("v_pk_add_f32 %0, %1, %2" : "=v"(d) : "v"(a), "v"(b)); return d;
}

// ---------------- Kernel 1: LayerNorm -> x(bf16), pair_bias^T (bf16*log2e) -
// pbT layout [h][k][j] so k_attn's C-fragment (lane=j, reg=k) reads are
// contiguous in j. lane0 of each half-wave writes one scalar.
__global__ __launch_bounds__(256) void k_ln(const float* __restrict__ act,
    const float* __restrict__ lnw, const float* __restrict__ lnb,
    const float* __restrict__ w2d, u16* __restrict__ xbf, u16* __restrict__ pbT) {
  int t = threadIdx.x;
  int l32 = t & 31;
  int r = blockIdx.x * 8 + (t >> 5);
  const float4 a = *(const float4*)(act + (size_t)r * CZ + l32 * 4);
  float s = (a.x + a.y) + (a.z + a.w);
  float s2 = (a.x * a.x + a.y * a.y) + (a.z * a.z + a.w * a.w);
  #pragma unroll
  for (int m = 16; m >= 1; m >>= 1) { s += __shfl_xor(s, m, 32); s2 += __shfl_xor(s2, m, 32); }
  float mu = s * (1.0f / CZ);
  float inv = rsqrtf(s2 * (1.0f / CZ) - mu * mu + LN_EPS);
  float4 w = *(const float4*)(lnw + l32 * 4);
  float4 b = *(const float4*)(lnb + l32 * 4);
  float4 xv;
  xv.x = (a.x - mu) * inv * w.x + b.x;
  xv.y = (a.y - mu) * inv * w.y + b.y;
  xv.z = (a.z - mu) * inv * w.z + b.z;
  xv.w = (a.w - mu) * inv * w.w + b.w;
  uint2 st; st.x = cvtpk(xv.x, xv.y); st.y = cvtpk(xv.z, xv.w);
  *(uint2*)(xbf + (size_t)r * CZ + l32 * 4) = st;
  int j = r / NN, k = r - j * NN;
  #pragma unroll
  for (int h = 0; h < NH; ++h) {
    float4 wd = *(const float4*)(w2d + h * CZ + l32 * 4);
    float p = (xv.x * wd.x + xv.y * wd.y) + (xv.z * wd.z + xv.w * wd.w);
    #pragma unroll
    for (int m = 16; m >= 1; m >>= 1) p += __shfl_xor(p, m, 32);
    if (l32 == 0) pbT[(size_t)h * NROWS + (size_t)k * NN + j] = f2bf(p * LOG2E);
  }
}

// ---------------- Kernel 2: MFMA projections, one mat per block ------------
__global__ __launch_bounds__(256) void k_projf(const u16* __restrict__ x,
    const float* __restrict__ wq, const float* __restrict__ wk,
    const float* __restrict__ wv, const float* __restrict__ wg,
    const float* __restrict__ bg,
    u16* __restrict__ qb, u16* __restrict__ kb,
    u16* __restrict__ vT, u16* __restrict__ gb) {
  __shared__ __align__(16) u16 wl[128][128];  // 32 KB
  __shared__ __align__(16) u16 xl[64][128];   // 16 KB
  int t = threadIdx.x;
  int lane = t & 63, wid = t >> 6;
  int jl = lane & 31, g = lane >> 5;
  int m = blockIdx.y;
  const float* W = (m == 0) ? wq : (m == 1) ? wk : (m == 2) ? wv : wg;
  float sc = (m == 0) ? QSCALE_L2 : 1.f;
  size_t tile0 = (size_t)blockIdx.x * 9;

  uint4 xr[4];
  {
    const uint4* src = (const uint4*)(x + tile0 * 64 * CZ);
    #pragma unroll
    for (int p = 0; p < 4; ++p) xr[p] = src[t + p * 256];
  }
  #pragma unroll
  for (int it = 0; it < 8; ++it) {
    int idx = t + it * 256;
    int e = idx >> 4, s = idx & 15;
    float4 f0 = *(const float4*)&W[e * CZ + s * 8];
    float4 f1 = *(const float4*)&W[e * CZ + s * 8 + 4];
    uint4 st;
    st.x = cvtpk(f0.x * sc, f0.y * sc); st.y = cvtpk(f0.z * sc, f0.w * sc);
    st.z = cvtpk(f1.x * sc, f1.y * sc); st.w = cvtpk(f1.z * sc, f1.w * sc);
    *(uint4*)&wl[e][(s ^ (e & 15)) * 8] = st;
  }

  int rfb = (wid & 1) * 32, efb = (wid >> 1) * 2;
  for (int it = 0; it < 9; ++it) {
    __syncthreads();
    #pragma unroll
    for (int p = 0; p < 4; ++p) {
      int q = t + p * 256; int r = q >> 4, s = q & 15;
      *(uint4*)&xl[r][(s ^ (r & 15)) * 8] = xr[p];
    }
    __syncthreads();
    if (it < 8) {
      const uint4* src = (const uint4*)(x + (tile0 + it + 1) * 64 * CZ);
      #pragma unroll
      for (int p = 0; p < 4; ++p) xr[p] = src[t + p * 256];
    }
    size_t row0 = (tile0 + it) * 64;

    f32x16 acc[2];
    #pragma unroll
    for (int ef = 0; ef < 2; ++ef)
      #pragma unroll
      for (int i = 0; i < 16; ++i) acc[ef][i] = 0.f;

    if (m == 2) {  // v: mfma(x, W^T) -> C lane = e, regs = row
      #pragma unroll
      for (int ks = 0; ks < 8; ++ks) {
        int r = rfb + jl;
        bf16x8 xa = *(const bf16x8*)&xl[r][((2 * ks + g) ^ (r & 15)) * 8];
        #pragma unroll
        for (int ef = 0; ef < 2; ++ef) {
          int e = (efb + ef) * 32 + jl;
          bf16x8 wf = *(const bf16x8*)&wl[e][((2 * ks + g) ^ (e & 15)) * 8];
          acc[ef] = __builtin_amdgcn_mfma_f32_32x32x16_bf16(xa, wf, acc[ef], 0, 0, 0);
        }
      }
      #pragma unroll
      for (int ef = 0; ef < 2; ++ef) {
        int e = (efb + ef) * 32 + jl;
        u16* dst = vT + (size_t)e * NROWS + row0 + rfb + 4 * g;
        #pragma unroll
        for (int rr = 0; rr < 4; ++rr) {
          uint2 st;
          st.x = cvtpk(acc[ef][4 * rr + 0], acc[ef][4 * rr + 1]);
          st.y = cvtpk(acc[ef][4 * rr + 2], acc[ef][4 * rr + 3]);
          *(uint2*)(dst + 8 * rr) = st;
        }
      }
    } else {  // q/k/g: mfma(W, x^T) -> C lane = row, regs = e
      #pragma unroll
      for (int ks = 0; ks < 8; ++ks) {
        int r = rfb + jl;
        bf16x8 xa = *(const bf16x8*)&xl[r][((2 * ks + g) ^ (r & 15)) * 8];
        #pragma unroll
        for (int ef = 0; ef < 2; ++ef) {
          int e = (efb + ef) * 32 + jl;
          bf16x8 wf = *(const bf16x8*)&wl[e][((2 * ks + g) ^ (e & 15)) * 8];
          acc[ef] = __builtin_amdgcn_mfma_f32_32x32x16_bf16(wf, xa, acc[ef], 0, 0, 0);
        }
      }
      u16* ob = (m == 0) ? qb : (m == 1) ? kb : gb;
      size_t row = row0 + rfb + jl;
      #pragma unroll
      for (int ef = 0; ef < 2; ++ef) {
        u16* dst = ob + row * CZ + (efb + ef) * 32 + 4 * g;
        #pragma unroll
        for (int rr = 0; rr < 4; ++rr) {
          float v0 = acc[ef][4 * rr + 0], v1 = acc[ef][4 * rr + 1];
          float v2 = acc[ef][4 * rr + 2], v3 = acc[ef][4 * rr + 3];
          if (m == 3) {
            float4 bv = *(const float4*)&bg[(efb + ef) * 32 + 8 * rr + 4 * g];
            v0 = sigm(v0 + bv.x); v1 = sigm(v1 + bv.y);
            v2 = sigm(v2 + bv.z); v3 = sigm(v3 + bv.w);
          }
          uint2 st; st.x = cvtpk(v0, v1); st.y = cvtpk(v2, v3);
          *(uint2*)(dst + 8 * rr) = st;
        }
      }
    }
  }
}

// ---------------- Kernel 3: MFMA attention, 12 waves x 1 j-frag ------------
// R7 structure (proven 143us). pb now bf16 TRANSPOSED [h][k][j]: lanes read
// consecutive j -> contiguous 64B per (reg,g); 16 scalar u16 loads per kt,
// issued before the QK MFMA so L2 latency hides under it. L2 bias traffic
// drops ~4x (1.8GB -> 443MB).
template<bool MASKED>
__device__ __forceinline__ void attn_core(const u16* ks, const u16* vs,
    const u16* pbw, const float* mrow4, int jl, int g,
    bf16x8 qf0, bf16x8 qf1, f32x16& oacc, float& mrun, float& lrun) {
  for (int kt = 0; kt < 12; ++kt) {
    const int k0 = kt * 32;
    bf16x8 ka0 = *(const bf16x8*)&ks[(k0 + jl) * 40 + 8 * g];
    bf16x8 ka1 = *(const bf16x8*)&ks[(k0 + jl) * 40 + 8 * g + 16];
    bf16x8 va0 = *(const bf16x8*)&vs[jl * 392 + k0 + 8 * g];
    bf16x8 va1 = *(const bf16x8*)&vs[jl * 392 + k0 + 16 + 8 * g];
    // pair-bias: pbT[k0+kl(r,g)][j0+jl]; kl = (r&3)+8*(r>>2)+4g
    float pv[16];
    {
      const int kb0 = (k0 + 4 * g) * NN;
      #pragma unroll
      for (int r = 0; r < 16; ++r) {
        int kl = (r & 3) + 8 * (r >> 2);
        pv[r] = bflo((u32)pbw[kb0 + kl * NN]);
      }
    }
    f32x16 sac;
    #pragma unroll
    for (int r = 0; r < 16; ++r) sac[r] = 0.f;
    __builtin_amdgcn_s_setprio(1);
    sac = __builtin_amdgcn_mfma_f32_32x32x16_bf16(ka0, qf0, sac, 0, 0, 0);
    sac = __builtin_amdgcn_mfma_f32_32x32x16_bf16(ka1, qf1, sac, 0, 0, 0);
    __builtin_amdgcn_s_setprio(0);
    f32x2 s2[8];
    #pragma unroll
    for (int rr = 0; rr < 4; ++rr) {
      s2[2 * rr + 0] = pkadd(f32x2{sac[4 * rr + 0], sac[4 * rr + 1]},
                             f32x2{pv[4 * rr + 0], pv[4 * rr + 1]});
      s2[2 * rr + 1] = pkadd(f32x2{sac[4 * rr + 2], sac[4 * rr + 3]},
                             f32x2{pv[4 * rr + 2], pv[4 * rr + 3]});
    }
    if (MASKED) {
      #pragma unroll
      for (int m4 = 0; m4 < 4; ++m4) {
        float4 mm = *(const float4*)(mrow4 + k0 + 8 * m4);
        s2[2 * m4 + 0] = pkadd(s2[2 * m4 + 0],
            f32x2{(mm.x - 1.f) * (1e9f * LOG2E), (mm.y - 1.f) * (1e9f * LOG2E)});
        s2[2 * m4 + 1] = pkadd(s2[2 * m4 + 1],
            f32x2{(mm.z - 1.f) * (1e9f * LOG2E), (mm.w - 1.f) * (1e9f * LOG2E)});
      }
    }
    float t0 = fmaxf(fmaxf(s2[0][0], s2[0][1]), fmaxf(s2[1][0], s2[1][1]));
    float t1 = fmaxf(fmaxf(s2[2][0], s2[2][1]), fmaxf(s2[3][0], s2[3][1]));
    float t2 = fmaxf(fmaxf(s2[4][0], s2[4][1]), fmaxf(s2[5][0], s2[5][1]));
    float t3 = fmaxf(fmaxf(s2[6][0], s2[6][1]), fmaxf(s2[7][0], s2[7][1]));
    float tmax = fmaxf(fmaxf(t0, t1), fmaxf(t2, t3));
    tmax = fmaxf(tmax, __shfl_xor(tmax, 32, 64));
    float mold = mrun;
    bool defer = __all(tmax <= mold + 8.f);
    float mnew = defer ? mold : fmaxf(mold, tmax);
    f32x2 nmw = f32x2{-mnew, -mnew};
    f32x2 p2[8];
    #pragma unroll
    for (int p8 = 0; p8 < 8; ++p8) {
      f32x2 d = pkadd(s2[p8], nmw);
      p2[p8] = f32x2{exp2fast(d[0]), exp2fast(d[1])};
    }
    f32x2 q0 = pkadd(p2[0], p2[1]), q1 = pkadd(p2[2], p2[3]);
    f32x2 q2 = pkadd(p2[4], p2[5]), q3 = pkadd(p2[6], p2[7]);
    q0 = pkadd(q0, q1); q2 = pkadd(q2, q3); q0 = pkadd(q0, q2);
    float psum = q0[0] + q0[1];
    if (!defer) {
      float rsc = exp2fast(mold - mnew);
      mrun = mnew;
      lrun = lrun * rsc + psum;
      #pragma unroll
      for (int r = 0; r < 16; ++r) oacc[r] *= rsc;
    } else {
      lrun += psum;
    }
    u32 A01 = cvtpk(p2[0][0], p2[0][1]), A23 = cvtpk(p2[1][0], p2[1][1]);
    u32 B01 = cvtpk(p2[2][0], p2[2][1]), B23 = cvtpk(p2[3][0], p2[3][1]);
    u32 C01 = cvtpk(p2[4][0], p2[4][1]), C23 = cvtpk(p2[5][0], p2[5][1]);
    u32 D01 = cvtpk(p2[6][0], p2[6][1]), D23 = cvtpk(p2[7][0], p2[7][1]);
    auto r0 = __builtin_amdgcn_permlane32_swap(A01, B01, false, false);
    auto r1 = __builtin_amdgcn_permlane32_swap(A23, B23, false, false);
    auto r2 = __builtin_amdgcn_permlane32_swap(C01, D01, false, false);
    auto r3 = __builtin_amdgcn_permlane32_swap(C23, D23, false, false);
    union { u32 w[4]; bf16x8 v; } b0, b1;
    b0.w[0] = r0[0]; b0.w[1] = r1[0]; b0.w[2] = r0[1]; b0.w[3] = r1[1];
    b1.w[0] = r2[0]; b1.w[1] = r3[0]; b1.w[2] = r2[1]; b1.w[3] = r3[1];
    __builtin_amdgcn_s_setprio(1);
    oacc = __builtin_amdgcn_mfma_f32_32x32x16_bf16(va0, b0.v, oacc, 0, 0, 0);
    oacc = __builtin_amdgcn_mfma_f32_32x32x16_bf16(va1, b1.v, oacc, 0, 0, 0);
    __builtin_amdgcn_s_setprio(0);
  }
}

__global__ __launch_bounds__(768) void k_attn(const u16* __restrict__ q,
    const u16* __restrict__ kmat, const u16* __restrict__ vT,
    const u16* __restrict__ pbT, const float* __restrict__ mask,
    u16* __restrict__ o) {
  __shared__ __align__(16) u16 ks[384 * 40];  // K rows padded to 40 bf16
  __shared__ __align__(16) u16 vs[32 * 392];  // V^T rows padded to 392 bf16
  int i = blockIdx.x, h = blockIdx.y;
  int t = threadIdx.x;
  size_t base = ((size_t)i * NN) * CZ + h * 32;
  {
    const u16* src = kmat + base;
    for (int idx = t; idx < 1536; idx += 768) {
      int row = idx >> 2, c = idx & 3;
      *(uint4*)&ks[row * 40 + c * 8] = *(const uint4*)(src + (size_t)row * CZ + c * 8);
    }
    const u16* vsrc = vT + (size_t)(h * 32) * NROWS + (size_t)i * NN;
    for (int idx = t; idx < 1536; idx += 768) {
      int d = idx / 48, c = idx % 48;
      *(uint4*)&vs[d * 392 + c * 8] = *(const uint4*)(vsrc + (size_t)d * NROWS + c * 8);
    }
  }
  int lane = t & 63, wid = t >> 6;  // wid 0..11
  int jl = lane & 31, g = lane >> 5;
  int j = wid * 32 + jl;
  const float* mrow = mask + (size_t)i * NN;
  bool m1 = true;
  #pragma unroll
  for (int c = 0; c < 6; ++c) m1 &= (mrow[lane + 64 * c] == 1.f);
  bool nomask = __all(m1);
  const u16* qp = q + base + (size_t)j * CZ + g * 8;
  bf16x8 qf0 = *(const bf16x8*)qp;
  bf16x8 qf1 = *(const bf16x8*)(qp + 16);
  __syncthreads();

  f32x16 oacc;
  #pragma unroll
  for (int r = 0; r < 16; ++r) oacc[r] = 0.f;
  float mrun = -3e38f, lrun = 0.f;
  const u16* pbw = pbT + (size_t)h * NROWS + wid * 32 + jl;  // + k*NN per reg
  if (nomask) attn_core<false>(ks, vs, pbw, mrow + 4 * g, jl, g, qf0, qf1, oacc, mrun, lrun);
  else        attn_core<true >(ks, vs, pbw, mrow + 4 * g, jl, g, qf0, qf1, oacc, mrun, lrun);

  float lt = lrun + __shfl_xor(lrun, 32, 64);
  float inv = 1.f / lt;
  u16* dst = o + (size_t)(i * NN + j) * CZ + h * 32 + 4 * g;
  #pragma unroll
  for (int q4 = 0; q4 < 4; ++q4) {
    uint2 st;
    st.x = cvtpk(oacc[4 * q4 + 0] * inv, oacc[4 * q4 + 1] * inv);
    st.y = cvtpk(oacc[4 * q4 + 2] * inv, oacc[4 * q4 + 3] * inv);
    *(uint2*)(dst + 8 * q4) = st;
  }
}

// ---------------- Kernel 4: MFMA out = (o*g) @ wo^T + bo  (fp32 out) -------
__global__ __launch_bounds__(256) void k_out(const u16* __restrict__ o,
    const u16* __restrict__ g, const float* __restrict__ wo,
    const float* __restrict__ bo, float* __restrict__ out) {
  __shared__ __align__(16) u16 wols[128][128];  // 32 KB
  __shared__ __align__(16) u16 tls[128][128];   // 32 KB
  int t = threadIdx.x;
  int lane = t & 63, wid = t >> 6, jl = lane & 31, gg = lane >> 5;
  size_t row0 = (size_t)blockIdx.x * 128;
  #pragma unroll
  for (int it = 0; it < 8; ++it) {
    int idx = t + it * 256; int c = idx >> 4, s = idx & 15;
    float4 f0 = *(const float4*)&wo[c * CZ + s * 8];
    float4 f1 = *(const float4*)&wo[c * CZ + s * 8 + 4];
    uint4 st; st.x = cvtpk(f0.x, f0.y); st.y = cvtpk(f0.z, f0.w);
    st.z = cvtpk(f1.x, f1.y); st.w = cvtpk(f1.z, f1.w);
    *(uint4*)&wols[c][(s ^ (c & 15)) * 8] = st;
  }
  #pragma unroll
  for (int it = 0; it < 8; ++it) {
    int idx = t + it * 256; int r = idx >> 4, s = idx & 15;
    uint4 uo = *(const uint4*)(o + (row0 + r) * CZ + s * 8);
    uint4 ug = *(const uint4*)(g + (row0 + r) * CZ + s * 8);
    uint4 st;
    st.x = cvtpk(bflo(uo.x) * bflo(ug.x), bfhi(uo.x) * bfhi(ug.x));
    st.y = cvtpk(bflo(uo.y) * bflo(ug.y), bfhi(uo.y) * bfhi(ug.y));
    st.z = cvtpk(bflo(uo.z) * bflo(ug.z), bfhi(uo.z) * bfhi(ug.z));
    st.w = cvtpk(bflo(uo.w) * bflo(ug.w), bfhi(uo.w) * bfhi(ug.w));
    *(uint4*)&tls[r][(s ^ (r & 15)) * 8] = st;
  }
  __syncthreads();
  f32x16 acc[4];
  #pragma unroll
  for (int cf = 0; cf < 4; ++cf)
    #pragma unroll
    for (int i = 0; i < 16; ++i) acc[cf][i] = 0.f;
  #pragma unroll
  for (int ks = 0; ks < 8; ++ks) {
    int r = wid * 32 + jl;
    bf16x8 tf = *(const bf16x8*)&tls[r][((2 * ks + gg) ^ (r & 15)) * 8];
    #pragma unroll
    for (int cf = 0; cf < 4; ++cf) {
      int c = cf * 32 + jl;
      bf16x8 wf = *(const bf16x8*)&wols[c][((2 * ks + gg) ^ (c & 15)) * 8];
      acc[cf] = __builtin_amdgcn_mfma_f32_32x32x16_bf16(wf, tf, acc[cf], 0, 0, 0);
    }
  }
  size_t row = row0 + wid * 32 + jl;
  #pragma unroll
  for (int cf = 0; cf < 4; ++cf)
    #pragma unroll
    for (int rr = 0; rr < 4; ++rr) {
      int c = cf * 32 + 8 * rr + 4 * gg;
      float4 bv = *(const float4*)&bo[c];
      float4 v;
      v.x = acc[cf][4 * rr + 0] + bv.x; v.y = acc[cf][4 * rr + 1] + bv.y;
      v.z = acc[cf][4 * rr + 2] + bv.z; v.w = acc[cf][4 * rr + 3] + bv.w;
      *(float4*)&out[row * CZ + c] = v;
    }
}

extern "C" void kernel_launch(void* const* d_in, const int* in_sizes, int n_in,
                              void* d_out, int out_size, void* d_ws, size_t ws_size,
                              hipStream_t stream) {
  const float* act  = (const float*)d_in[0];
  const float* mask = (const float*)d_in[1];
  const float* ln_w = (const float*)d_in[2];
  const float* ln_b = (const float*)d_in[3];
  const float* w2d  = (const float*)d_in[4];
  const float* wq   = (const float*)d_in[5];
  const float* wk   = (const float*)d_in[6];
  const float* wv   = (const float*)d_in[7];
  const float* wg   = (const float*)d_in[8];
  const float* bg   = (const float*)d_in[9];
  const float* wo   = (const float*)d_in[10];
  const float* bo   = (const float*)d_in[11];
  float* out = (float*)d_out;

  char* ws = (char*)d_ws;
  const size_t sz = (size_t)NROWS * CZ * 2;
  u16* xbf = (u16*)ws;
  u16* qb  = (u16*)(ws + 1 * sz);
  u16* kb  = (u16*)(ws + 2 * sz);
  u16* vTb = (u16*)(ws + 3 * sz);
  u16* gb  = (u16*)(ws + 4 * sz);
  u16* ob  = (u16*)(ws + 5 * sz);
  u16* pbf = (u16*)(ws + 6 * sz);

  k_ln<<<NROWS / 8, 256, 0, stream>>>(act, ln_w, ln_b, w2d, xbf, pbf);
  dim3 gp(256, 4);
  k_projf<<<gp, 256, 0, stream>>>(xbf, wq, wk, wv, wg, bg, qb, kb, vTb, gb);
  dim3 ga(NN, NH);
  k_attn<<<ga, 768, 0, stream>>>(qb, kb, vTb, pbf, mask, ob);
  k_out<<<NROWS / 128, 256, 0, stream>>>(ob, gb, wo, bo, out);
}